// Round 12
// baseline (456.334 us; speedup 1.0000x reference)
//
#include <hip/hip_runtime.h>

// WKV7 (RWKV-7) forward scan. T=2048, H=64, D=64.
// R12: SHARED STAGING. R5-R11 invariance isolated the bottleneck as per-CU
// vmem op count (28/CU/step: 4 independent waves x 7 ops). Now: block =
// (head, quarter) = 256 blocks x 256 threads (1 block/CU, 4 waves x 4 rows).
// Per step ONE duty wave (rotating by t&3) stages the block's 6x64-float
// vectors via global_load_lds -> 7 vmem ops/CU/step. One s_barrier/step;
// guard wave (t+2)&3 does counted vmcnt(12) BEFORE the barrier; stage goes
// AFTER the barrier (readers of the recycled slot finished last body).
// Compute body = R9 verbatim (dual interleaved DPP reduce, 2-deep ds_read).

typedef float f32x4 __attribute__((ext_vector_type(4)));

constexpr int T_LEN = 2048;
constexpr int DD    = 64;
constexpr int HD    = 64 * 64;   // 4096

#define AS1 __attribute__((address_space(1)))
#define AS3 __attribute__((address_space(3)))

struct Buf { f32x4 r, e, k, a, b; float vv; };

__global__ __launch_bounds__(256)
void exp_kernel(const float4* __restrict__ w, float4* __restrict__ ew, int n4) {
  int i = blockIdx.x * blockDim.x + threadIdx.x;
  int stride = gridDim.x * blockDim.x;
  for (; i < n4; i += stride) {
    float4 x = w[i];
    float4 o;
    o.x = __expf(x.x); o.y = __expf(x.y); o.z = __expf(x.z); o.w = __expf(x.w);
    ew[i] = o;
  }
}

template<int CTRL>
__device__ __forceinline__ float dpp_add(float x) {
  int y = __builtin_amdgcn_update_dpp(0, __float_as_int(x), CTRL, 0xf, 0xf, true);
  return x + __int_as_float(y);
}

// Serial 16-lane reduce (prologue only).
__device__ __forceinline__ float row16_reduce(float x) {
  x = dpp_add<0xB1>(x);    // quad_perm [1,0,3,2]
  x = dpp_add<0x4E>(x);    // quad_perm [2,3,0,1]
  x = dpp_add<0x141>(x);   // row_half_mirror
  x = dpp_add<0x140>(x);   // row_mirror
  return x;
}

// Two interleaved row-of-16 reductions; s_nop 1 covers the entry
// VALU-write -> DPP-read hazard (R8 lesson).
__device__ __forceinline__ void duo_reduce(float& a, float& b) {
  float t0, t1;
  asm volatile(
    "s_nop 1\n\t"
    "v_mov_b32_dpp %2, %0 quad_perm:[1,0,3,2] row_mask:0xf bank_mask:0xf\n\t"
    "v_mov_b32_dpp %3, %1 quad_perm:[1,0,3,2] row_mask:0xf bank_mask:0xf\n\t"
    "s_nop 0\n\t"
    "v_add_f32 %0, %0, %2\n\t"
    "v_add_f32 %1, %1, %3\n\t"
    "s_nop 0\n\t"
    "v_mov_b32_dpp %2, %0 quad_perm:[2,3,0,1] row_mask:0xf bank_mask:0xf\n\t"
    "v_mov_b32_dpp %3, %1 quad_perm:[2,3,0,1] row_mask:0xf bank_mask:0xf\n\t"
    "s_nop 0\n\t"
    "v_add_f32 %0, %0, %2\n\t"
    "v_add_f32 %1, %1, %3\n\t"
    "s_nop 0\n\t"
    "v_mov_b32_dpp %2, %0 row_half_mirror row_mask:0xf bank_mask:0xf\n\t"
    "v_mov_b32_dpp %3, %1 row_half_mirror row_mask:0xf bank_mask:0xf\n\t"
    "s_nop 0\n\t"
    "v_add_f32 %0, %0, %2\n\t"
    "v_add_f32 %1, %1, %3\n\t"
    "s_nop 0\n\t"
    "v_mov_b32_dpp %2, %0 row_mirror row_mask:0xf bank_mask:0xf\n\t"
    "v_mov_b32_dpp %3, %1 row_mirror row_mask:0xf bank_mask:0xf\n\t"
    "s_nop 0\n\t"
    "v_add_f32 %0, %0, %2\n\t"
    "v_add_f32 %1, %1, %3"
    : "+v"(a), "+v"(b), "=&v"(t0), "=&v"(t1));
}

__device__ __forceinline__ float dot4(const f32x4& x, const f32x4& y) {
  return fmaf(x[3], y[3], fmaf(x[2], y[2], fmaf(x[1], y[1], x[0] * y[0])));
}

__device__ __forceinline__ void gload_lds(const float* g, const float* l) {
  __builtin_amdgcn_global_load_lds((const AS1 unsigned*)g, (AS3 unsigned*)l, 4, 0, 0);
}

__global__ __launch_bounds__(256, 1)
void wkv7_scan(const float* __restrict__ R, const float* __restrict__ EW,
               const float* __restrict__ K, const float* __restrict__ V,
               const float* __restrict__ A, const float* __restrict__ B,
               const float* __restrict__ S0, float* __restrict__ X,
               float* __restrict__ SOUT)
{
  // 8 slots x (5 vectors + v) x 64 floats = 3072 floats = 12 KB
  __shared__ float smem[3072];

  const int blk = blockIdx.x;          // 0..255
  const int q   = blk >> 6;            // quarter 0..3
  const int h   = blk & 63;            // head 0..63  (all 4 q's of a head on
                                       //  XCD h&7: 64 ≡ 0 mod 8)
  const int tid  = threadIdx.x;        // 0..255
  const int wid  = tid >> 6;           // wave 0..3
  const int lane = tid & 63;
  const int cg   = lane & 15;          // cols [cg*4, cg*4+4)
  const int rl   = lane >> 4;          // local row 0..3
  const int row  = q * 16 + wid * 4 + rl;   // 0..63
  const int c0   = cg * 4;

  const int laneoff = h * DD + lane;   // per-lane global offset (staging)

  const unsigned lb  = (unsigned)(uintptr_t)(AS3 float*)&smem[0];
  const unsigned vab = lb + (unsigned)(cg * 16);   // vector-read base
  const unsigned vvb = lb + (unsigned)(row * 4);   // v-read base (offset:1280)

  const int voffb = (h * DD + row) * 4;   // byte offset of (h,row) in one step

  f32x4 s;
  {
    const f32x4* sp = (const f32x4*)(S0 + (size_t)h * DD * DD + row * DD + c0);
    s = *sp;
  }

  auto stage = [&](int tt, int slot) {
    const size_t o = (size_t)tt * HD + laneoff;
    const float* l = &smem[slot * 384];
    gload_lds(R  + o, l);
    gload_lds(EW + o, l + 64);
    gload_lds(K  + o, l + 128);
    gload_lds(A  + o, l + 192);
    gload_lds(B  + o, l + 256);
    gload_lds(V  + o, l + 320);
  };

  auto lds_read = [&](Buf& d, int slot) {
    unsigned va = vab + (unsigned)(slot * 1536);
    unsigned vv = vvb + (unsigned)(slot * 1536);
    asm volatile(
      "ds_read_b128 %0, %6\n\t"
      "ds_read_b128 %1, %6 offset:256\n\t"
      "ds_read_b128 %2, %6 offset:512\n\t"
      "ds_read_b128 %3, %6 offset:768\n\t"
      "ds_read_b128 %4, %6 offset:1024\n\t"
      "ds_read_b32  %5, %7 offset:1280"
      : "=&v"(d.r), "=&v"(d.e), "=&v"(d.k), "=&v"(d.a), "=&v"(d.b), "=&v"(d.vv)
      : "v"(va), "v"(vv) : "memory");
  };

  auto wait_nx1 = [&](Buf& d) {
    asm volatile("s_waitcnt lgkmcnt(6)"
                 : "+v"(d.r), "+v"(d.e), "+v"(d.k), "+v"(d.a), "+v"(d.b),
                   "+v"(d.vv));
  };

  float sa;                 // sa_t = S_{t-1}.a_t, ready at body t entry
  float yprev = 0.0f;       // y_{t-1}, stored at body t
  int   yoff_prev = 2047 * (HD * 4) + voffb;  // body-0 dummy target
                                              // (epilogue overwrites)

  // PHASE is t&3 (compile-time per unroll position).
  // Duty wave (stages t+8)   = PHASE.
  // Guard wave (vmcnt for t+2) = (PHASE+2)&3: its ops newer than stage(t+2)
  //   [issued at its body t-6] = 6 y-stores (bodies t-6..t-1) + 1 stage
  //   (body t-2, 6 loads) = 12 -> vmcnt(12). Bodies with t+2 <= 7 are
  //   covered by the prologue's vmcnt(0)+barrier, so the uniform guard is
  //   safe (merely trivially-true early).
  auto body = [&](Buf& cur, Buf& nx1, Buf& nx2, int t, int PHASE) {
    if (wid == ((PHASE + 2) & 3)) {
      asm volatile("s_waitcnt vmcnt(12)" ::: "memory");
    }
    __builtin_amdgcn_s_barrier();
    if (wid == PHASE) {
      stage((t + 8) & (T_LEN - 1), t & 7);   // slot t&7: all reads of it
    }                                         // finished last body + barrier
    lds_read(nx2, (t + 2) & 7);
    wait_nx1(nx1);

    // ---- state update for step t (sa ready since last body) ----
    const float vv = cur.vv;
    s[0] = fmaf(cur.e[0], s[0], fmaf(sa, cur.b[0], vv * cur.k[0]));
    s[1] = fmaf(cur.e[1], s[1], fmaf(sa, cur.b[1], vv * cur.k[1]));
    s[2] = fmaf(cur.e[2], s[2], fmaf(sa, cur.b[2], vv * cur.k[2]));
    s[3] = fmaf(cur.e[3], s[3], fmaf(sa, cur.b[3], vv * cur.k[3]));

    // ---- both dots (partials) ----
    float qd = dot4(s, nx1.a);   // -> sa_{t+1}
    float yd = dot4(s, cur.r);   // -> y_t

    // ---- store y_{t-1} while reductions run ----
    if (cg == 0) {
      asm volatile("global_store_dword %0, %1, %2"
                   :: "v"(yoff_prev), "v"(yprev), "s"(X) : "memory");
    }

    // ---- interleaved dual reduction ----
    duo_reduce(qd, yd);
    sa    = qd;
    yprev = yd;
    yoff_prev = t * (HD * 4) + voffb;
  };

  // Prologue: wave w stages slots w and w+4 (duty mapping: slot s is staged
  // by wave s&3), then everyone drains and barriers.
  stage(wid, wid);
  __builtin_amdgcn_sched_barrier(0);
  stage(wid + 4, wid + 4);
  __builtin_amdgcn_sched_barrier(0);
  asm volatile("s_waitcnt vmcnt(0)" ::: "memory");
  __builtin_amdgcn_s_barrier();

  Buf B0, B1, B2, B3;
  lds_read(B0, 0);
  lds_read(B1, 1);
  asm volatile("s_waitcnt lgkmcnt(0)"
               : "+v"(B0.r), "+v"(B0.e), "+v"(B0.k), "+v"(B0.a), "+v"(B0.b),
                 "+v"(B0.vv), "+v"(B1.a));

  // sa_0 = S_init . a_0 (prologue pays one serial reduce)
  sa = row16_reduce(dot4(s, B0.a));

  for (int t = 0; t < T_LEN; t += 4) {
    body(B0, B1, B2, t,     0);
    body(B1, B2, B3, t + 1, 1);
    body(B2, B3, B0, t + 2, 2);
    body(B3, B0, B1, t + 3, 3);
  }

  // Epilogue: final y (t=2047) — overwrites body-0's dummy store.
  if (cg == 0) {
    asm volatile("global_store_dword %0, %1, %2"
                 :: "v"(yoff_prev), "v"(yprev), "s"(X) : "memory");
  }

  *(f32x4*)(SOUT + (size_t)h * DD * DD + row * DD + c0) = s;
}

extern "C" void kernel_launch(void* const* d_in, const int* in_sizes, int n_in,
                              void* d_out, int out_size, void* d_ws, size_t ws_size,
                              hipStream_t stream) {
  // setup_inputs order: seq_length, r, w, k, v, a, b, state2
  const float* r  = (const float*)d_in[1];
  const float* w  = (const float*)d_in[2];
  const float* k  = (const float*)d_in[3];
  const float* v  = (const float*)d_in[4];
  const float* a  = (const float*)d_in[5];
  const float* b  = (const float*)d_in[6];
  const float* s0 = (const float*)d_in[7];

  float* x    = (float*)d_out;                     // (T, H, 1, D)
  float* sout = x + (size_t)T_LEN * HD;            // (H, D, D)

  float* ew = (float*)d_ws;
  (void)ws_size; (void)in_sizes; (void)n_in;

  int n4 = T_LEN * HD / 4;
  hipLaunchKernelGGL(exp_kernel, dim3(1024), dim3(256), 0, stream,
                     (const float4*)w, (float4*)ew, n4);
  hipLaunchKernelGGL(wkv7_scan, dim3(256), dim3(256), 0, stream,
                     r, ew, k, v, a, b, s0, x, sout);
}

// Round 13
// 433.561 us; speedup vs baseline: 1.0525x; 1.0525x over previous
//
#include <hip/hip_runtime.h>

// WKV7 (RWKV-7) forward scan. T=2048, H=64, D=64.
// R13: TLP. R5-R12 invariance (time ~440-520 cyc/step regardless of body,
// chain, staging, vmem-op count) fits one model: 1 wave/SIMD, in-order
// issue, ~250-300 cyc/step of dependency bubbles with NOTHING to fill them.
// Now: 2048 blocks x 64 threads (2 waves/SIMD co-resident). Wave = (head,
// 2-row block); lane owns 2 cols (cg=lane&31); row reduce = 4 DPP levels
// + ds_swizzle xor-16 (lanes 0-31 / 32-63 swizzle independently, so each
// row's 32 lanes combine correctly). Body/machinery otherwise = R9.

typedef float f32x2 __attribute__((ext_vector_type(2)));

constexpr int T_LEN = 2048;
constexpr int DD    = 64;
constexpr int HD    = 64 * 64;   // 4096

#define AS1 __attribute__((address_space(1)))
#define AS3 __attribute__((address_space(3)))

struct Buf { f32x2 r, e, k, a, b; float vv; };

__global__ __launch_bounds__(256)
void exp_kernel(const float4* __restrict__ w, float4* __restrict__ ew, int n4) {
  int i = blockIdx.x * blockDim.x + threadIdx.x;
  int stride = gridDim.x * blockDim.x;
  for (; i < n4; i += stride) {
    float4 x = w[i];
    float4 o;
    o.x = __expf(x.x); o.y = __expf(x.y); o.z = __expf(x.z); o.w = __expf(x.w);
    ew[i] = o;
  }
}

template<int CTRL>
__device__ __forceinline__ float dpp_add(float x) {
  int y = __builtin_amdgcn_update_dpp(0, __float_as_int(x), CTRL, 0xf, 0xf, true);
  return x + __int_as_float(y);
}

// 16-lane sum (prologue helper).
__device__ __forceinline__ float row16_reduce(float x) {
  x = dpp_add<0xB1>(x);    // quad_perm [1,0,3,2]
  x = dpp_add<0x4E>(x);    // quad_perm [2,3,0,1]
  x = dpp_add<0x141>(x);   // row_half_mirror
  x = dpp_add<0x140>(x);   // row_mirror
  return x;
}

// Two interleaved 32-lane reductions: 4 DPP levels + ds_swizzle xor-16.
// s_nop 1 at entry covers the VALU-write -> DPP-read hazard (R8 lesson).
// ds_swizzle stays within each 32-lane half => row0 (lanes 0-31) and row1
// (lanes 32-63) reduce independently.
__device__ __forceinline__ void duo_reduce32(float& a, float& b) {
  float t0, t1;
  asm volatile(
    "s_nop 1\n\t"
    "v_mov_b32_dpp %2, %0 quad_perm:[1,0,3,2] row_mask:0xf bank_mask:0xf\n\t"
    "v_mov_b32_dpp %3, %1 quad_perm:[1,0,3,2] row_mask:0xf bank_mask:0xf\n\t"
    "s_nop 0\n\t"
    "v_add_f32 %0, %0, %2\n\t"
    "v_add_f32 %1, %1, %3\n\t"
    "s_nop 0\n\t"
    "v_mov_b32_dpp %2, %0 quad_perm:[2,3,0,1] row_mask:0xf bank_mask:0xf\n\t"
    "v_mov_b32_dpp %3, %1 quad_perm:[2,3,0,1] row_mask:0xf bank_mask:0xf\n\t"
    "s_nop 0\n\t"
    "v_add_f32 %0, %0, %2\n\t"
    "v_add_f32 %1, %1, %3\n\t"
    "s_nop 0\n\t"
    "v_mov_b32_dpp %2, %0 row_half_mirror row_mask:0xf bank_mask:0xf\n\t"
    "v_mov_b32_dpp %3, %1 row_half_mirror row_mask:0xf bank_mask:0xf\n\t"
    "s_nop 0\n\t"
    "v_add_f32 %0, %0, %2\n\t"
    "v_add_f32 %1, %1, %3\n\t"
    "s_nop 0\n\t"
    "v_mov_b32_dpp %2, %0 row_mirror row_mask:0xf bank_mask:0xf\n\t"
    "v_mov_b32_dpp %3, %1 row_mirror row_mask:0xf bank_mask:0xf\n\t"
    "s_nop 0\n\t"
    "v_add_f32 %0, %0, %2\n\t"
    "v_add_f32 %1, %1, %3\n\t"
    "ds_swizzle_b32 %2, %0 offset:0x401F\n\t"
    "ds_swizzle_b32 %3, %1 offset:0x401F\n\t"
    "s_waitcnt lgkmcnt(0)\n\t"
    "v_add_f32 %0, %0, %2\n\t"
    "v_add_f32 %1, %1, %3"
    : "+v"(a), "+v"(b), "=&v"(t0), "=&v"(t1) :: "memory");
}

__device__ __forceinline__ float dot2(const f32x2& x, const f32x2& y) {
  return fmaf(x[1], y[1], x[0] * y[0]);
}

__device__ __forceinline__ void gload_lds(const float* g, const float* l) {
  __builtin_amdgcn_global_load_lds((const AS1 unsigned*)g, (AS3 unsigned*)l, 4, 0, 0);
}

__global__ __launch_bounds__(64, 2)
void wkv7_scan(const float* __restrict__ R, const float* __restrict__ EW,
               const float* __restrict__ K, const float* __restrict__ V,
               const float* __restrict__ A, const float* __restrict__ B,
               const float* __restrict__ S0, float* __restrict__ X,
               float* __restrict__ SOUT)
{
  // 8 slots x (5 vectors + v) x 64 floats = 3072 floats = 12 KB
  // 8 blocks/CU co-resident -> 96 KB of 160 KB LDS.
  __shared__ float smem[3072];

  const int blk = blockIdx.x;          // 0..2047
  const int xcd = blk & 7;
  const int m   = blk >> 3;            // 0..255
  const int h   = xcd * 8 + (m & 7);   // head 0..63 (co-located per XCD)
  const int sub = m >> 3;              // 2-row block 0..31

  const int lane = threadIdx.x;        // 0..63
  const int cg   = lane & 31;          // col group -> cols [cg*2, cg*2+2)
  const int rl   = lane >> 5;          // local row 0..1
  const int row  = sub * 2 + rl;       // 0..63
  const int c0   = cg * 2;

  const int laneoff = h * DD + lane;   // per-lane global offset (staging)

  const unsigned lb  = (unsigned)(uintptr_t)(AS3 float*)&smem[0];
  const unsigned vab = lb + (unsigned)(cg * 8);    // vector-read base
  const unsigned vvb = lb + (unsigned)(row * 4);   // v-read base (offset:1280)

  const int voffb = (h * DD + row) * 4;   // byte offset of (h,row) in one step

  f32x2 s;
  {
    const f32x2* sp = (const f32x2*)(S0 + (size_t)h * DD * DD + row * DD + c0);
    s = *sp;
  }

  auto stage = [&](int tt, int slot) {
    const size_t o = (size_t)tt * HD + laneoff;
    const float* l = &smem[slot * 384];
    gload_lds(R  + o, l);
    gload_lds(EW + o, l + 64);
    gload_lds(K  + o, l + 128);
    gload_lds(A  + o, l + 192);
    gload_lds(B  + o, l + 256);
    gload_lds(V  + o, l + 320);
  };

  auto lds_read = [&](Buf& d, int slot) {
    unsigned va = vab + (unsigned)(slot * 1536);
    unsigned vv = vvb + (unsigned)(slot * 1536);
    asm volatile(
      "ds_read_b64 %0, %6\n\t"
      "ds_read_b64 %1, %6 offset:256\n\t"
      "ds_read_b64 %2, %6 offset:512\n\t"
      "ds_read_b64 %3, %6 offset:768\n\t"
      "ds_read_b64 %4, %6 offset:1024\n\t"
      "ds_read_b32 %5, %7 offset:1280"
      : "=&v"(d.r), "=&v"(d.e), "=&v"(d.k), "=&v"(d.a), "=&v"(d.b), "=&v"(d.vv)
      : "v"(va), "v"(vv) : "memory");
  };

  auto wait_nx1 = [&](Buf& d) {
    asm volatile("s_waitcnt lgkmcnt(6)"
                 : "+v"(d.r), "+v"(d.e), "+v"(d.k), "+v"(d.a), "+v"(d.b),
                   "+v"(d.vv));
  };

  float sa;                 // sa_t = S_{t-1}.a_t, ready at body t entry
  float yprev = 0.0f;       // y_{t-1}, stored at body t
  int   yoff_prev = 2047 * (HD * 4) + voffb;  // body-0 dummy target
                                              // (epilogue overwrites)

  auto body = [&](Buf& cur, Buf& nx1, Buf& nx2, int t) {
    // slot (t+2)&7 resident: staged at body t-6; bodies t-5..t-1 issued
    // 5 x (6 loads + 1 store) = 35 newer vmem ops; vmcnt(30) is safe.
    asm volatile("s_waitcnt vmcnt(30)" ::: "memory");
    lds_read(nx2, (t + 2) & 7);
    wait_nx1(nx1);

    // ---- state update for step t (sa ready since last body) ----
    const float vv = cur.vv;
    s[0] = fmaf(cur.e[0], s[0], fmaf(sa, cur.b[0], vv * cur.k[0]));
    s[1] = fmaf(cur.e[1], s[1], fmaf(sa, cur.b[1], vv * cur.k[1]));

    // ---- both dots (partials over this lane's 2 cols) ----
    float qd = dot2(s, nx1.a);   // -> sa_{t+1}
    float yd = dot2(s, cur.r);   // -> y_t

    // ---- store y_{t-1} while reductions run ----
    if (cg == 0) {   // lanes 0 and 32: one store per row
      asm volatile("global_store_dword %0, %1, %2"
                   :: "v"(yoff_prev), "v"(yprev), "s"(X) : "memory");
    }
    stage((t + 8) & (T_LEN - 1), t & 7);

    // ---- interleaved dual 32-lane reduction ----
    duo_reduce32(qd, yd);
    sa    = qd;
    yprev = yd;
    yoff_prev = t * (HD * 4) + voffb;
  };

  // Prologue: fill ring (issue order = count order).
  for (int i = 0; i < 8; ++i) {
    stage(i, i);
    __builtin_amdgcn_sched_barrier(0);
  }
  asm volatile("s_waitcnt vmcnt(36)" ::: "memory");  // stages 0,1 done

  Buf B0, B1, B2, B3;
  lds_read(B0, 0);
  lds_read(B1, 1);
  asm volatile("s_waitcnt lgkmcnt(0)"
               : "+v"(B0.r), "+v"(B0.e), "+v"(B0.k), "+v"(B0.a), "+v"(B0.b),
                 "+v"(B0.vv), "+v"(B1.a));

  // sa_0 = S_init . a_0 (prologue pays one serial 32-lane reduce)
  sa = row16_reduce(dot2(s, B0.a));
  sa += __shfl_xor(sa, 16);

  for (int t = 0; t < T_LEN; t += 4) {
    body(B0, B1, B2, t);
    body(B1, B2, B3, t + 1);
    body(B2, B3, B0, t + 2);
    body(B3, B0, B1, t + 3);
  }

  // Epilogue: final y (t=2047) — overwrites body-0's dummy store.
  if (cg == 0) {
    asm volatile("global_store_dword %0, %1, %2"
                 :: "v"(yoff_prev), "v"(yprev), "s"(X) : "memory");
  }

  *(f32x2*)(SOUT + (size_t)h * DD * DD + row * DD + c0) = s;
}

extern "C" void kernel_launch(void* const* d_in, const int* in_sizes, int n_in,
                              void* d_out, int out_size, void* d_ws, size_t ws_size,
                              hipStream_t stream) {
  // setup_inputs order: seq_length, r, w, k, v, a, b, state2
  const float* r  = (const float*)d_in[1];
  const float* w  = (const float*)d_in[2];
  const float* k  = (const float*)d_in[3];
  const float* v  = (const float*)d_in[4];
  const float* a  = (const float*)d_in[5];
  const float* b  = (const float*)d_in[6];
  const float* s0 = (const float*)d_in[7];

  float* x    = (float*)d_out;                     // (T, H, 1, D)
  float* sout = x + (size_t)T_LEN * HD;            // (H, D, D)

  float* ew = (float*)d_ws;
  (void)ws_size; (void)in_sizes; (void)n_in;

  int n4 = T_LEN * HD / 4;
  hipLaunchKernelGGL(exp_kernel, dim3(1024), dim3(256), 0, stream,
                     (const float4*)w, (float4*)ew, n4);
  hipLaunchKernelGGL(wkv7_scan, dim3(2048), dim3(64), 0, stream,
                     r, ew, k, v, a, b, s0, x, sout);
}

// Round 14
// 291.022 us; speedup vs baseline: 1.5680x; 1.4898x over previous
//
#include <hip/hip_runtime.h>

// WKV7 (RWKV-7) forward scan. T=2048, H=64, D=64.
// R14: vmem-op-count test, barrier-free. Theory from R5-R13 invariance: the
// CU services vmem wave-ops at ~15 cyc/op; at 25 ops/CU/step (4 waves x
// (6 gload_lds + 1 store)) that's ~375 cyc/step = the observed wall.
// Fix: global_load_lds WIDTH=16 with lane-grouped sources -- op1 carries
// R/EW/K/A (lane group g=lane>>4 sources array g at sub*16B; LDS dest
// base+lane*16 bins each array into its 256B chunk), op2 carries B/V
// (+dup pad). 6 loads/step -> 2; per-CU 25 -> 12 ops/step.
// Everything else = R9 (best verified): 8-slot ring (now 2KB/slot, 16KB),
// 3-deep reg buffers, dual interleaved DPP reduce, y pipelined one body.
// vmcnt rebase: body guard vmcnt(15) (5 bodies x 3 ops), prologue vmcnt(12).

typedef float f32x4 __attribute__((ext_vector_type(4)));

constexpr int T_LEN = 2048;
constexpr int DD    = 64;
constexpr int HD    = 64 * 64;   // 4096

#define AS1 __attribute__((address_space(1)))
#define AS3 __attribute__((address_space(3)))

struct Buf { f32x4 r, e, k, a, b; float vv; };

__global__ __launch_bounds__(256)
void exp_kernel(const float4* __restrict__ w, float4* __restrict__ ew, int n4) {
  int i = blockIdx.x * blockDim.x + threadIdx.x;
  int stride = gridDim.x * blockDim.x;
  for (; i < n4; i += stride) {
    float4 x = w[i];
    float4 o;
    o.x = __expf(x.x); o.y = __expf(x.y); o.z = __expf(x.z); o.w = __expf(x.w);
    ew[i] = o;
  }
}

template<int CTRL>
__device__ __forceinline__ float dpp_add(float x) {
  int y = __builtin_amdgcn_update_dpp(0, __float_as_int(x), CTRL, 0xf, 0xf, true);
  return x + __int_as_float(y);
}

// Serial 16-lane reduce (prologue only).
__device__ __forceinline__ float row16_reduce(float x) {
  x = dpp_add<0xB1>(x);    // quad_perm [1,0,3,2]
  x = dpp_add<0x4E>(x);    // quad_perm [2,3,0,1]
  x = dpp_add<0x141>(x);   // row_half_mirror
  x = dpp_add<0x140>(x);   // row_mirror
  return x;
}

// Two interleaved row-of-16 reductions; s_nop 1 covers the entry
// VALU-write -> DPP-read hazard (R8 lesson).
__device__ __forceinline__ void duo_reduce(float& a, float& b) {
  float t0, t1;
  asm volatile(
    "s_nop 1\n\t"
    "v_mov_b32_dpp %2, %0 quad_perm:[1,0,3,2] row_mask:0xf bank_mask:0xf\n\t"
    "v_mov_b32_dpp %3, %1 quad_perm:[1,0,3,2] row_mask:0xf bank_mask:0xf\n\t"
    "s_nop 0\n\t"
    "v_add_f32 %0, %0, %2\n\t"
    "v_add_f32 %1, %1, %3\n\t"
    "s_nop 0\n\t"
    "v_mov_b32_dpp %2, %0 quad_perm:[2,3,0,1] row_mask:0xf bank_mask:0xf\n\t"
    "v_mov_b32_dpp %3, %1 quad_perm:[2,3,0,1] row_mask:0xf bank_mask:0xf\n\t"
    "s_nop 0\n\t"
    "v_add_f32 %0, %0, %2\n\t"
    "v_add_f32 %1, %1, %3\n\t"
    "s_nop 0\n\t"
    "v_mov_b32_dpp %2, %0 row_half_mirror row_mask:0xf bank_mask:0xf\n\t"
    "v_mov_b32_dpp %3, %1 row_half_mirror row_mask:0xf bank_mask:0xf\n\t"
    "s_nop 0\n\t"
    "v_add_f32 %0, %0, %2\n\t"
    "v_add_f32 %1, %1, %3\n\t"
    "s_nop 0\n\t"
    "v_mov_b32_dpp %2, %0 row_mirror row_mask:0xf bank_mask:0xf\n\t"
    "v_mov_b32_dpp %3, %1 row_mirror row_mask:0xf bank_mask:0xf\n\t"
    "s_nop 0\n\t"
    "v_add_f32 %0, %0, %2\n\t"
    "v_add_f32 %1, %1, %3"
    : "+v"(a), "+v"(b), "=&v"(t0), "=&v"(t1));
}

__device__ __forceinline__ float dot4(const f32x4& x, const f32x4& y) {
  return fmaf(x[3], y[3], fmaf(x[2], y[2], fmaf(x[1], y[1], x[0] * y[0])));
}

__device__ __forceinline__ void gload_lds16(const float* g, const float* l) {
  __builtin_amdgcn_global_load_lds((const AS1 unsigned*)g, (AS3 unsigned*)l, 16, 0, 0);
}

__global__ __launch_bounds__(64, 1)
void wkv7_scan(const float* __restrict__ R, const float* __restrict__ EW,
               const float* __restrict__ K, const float* __restrict__ V,
               const float* __restrict__ A, const float* __restrict__ B,
               const float* __restrict__ S0, float* __restrict__ X,
               float* __restrict__ SOUT)
{
  // 8 slots x 512 floats (2KB: R|EW|K|A|B|V|pad) = 16 KB
  __shared__ float smem[4096];

  const int blk = blockIdx.x;          // 0..1023
  // XCD co-location: 8 whole heads (16 row-blocks each) per XCD for L2 reuse.
  const int xcd = blk & 7;
  const int m   = blk >> 3;            // 0..127
  const int h   = xcd * 8 + (m & 7);   // head 0..63
  const int br  = m >> 3;              // row block 0..15

  const int lane = threadIdx.x;        // 0..63
  const int cg   = lane & 15;          // cols [cg*4, cg*4+4)
  const int rl   = lane >> 4;          // local row 0..3
  const int row  = br * 4 + rl;        // 0..63
  const int c0   = cg * 4;

  // Staging source pointers: op1 lane-groups source R/EW/K/A, op2 B/V
  // (upper 32 lanes duplicate V into the pad region -- harmless).
  const int g1  = lane >> 4;           // source-array group 0..3
  const int sub = lane & 15;           // 16B chunk index within the array
  const float* base1 = (g1 == 0) ? R : (g1 == 1) ? EW : (g1 == 2) ? K : A;
  const float* base2 = (g1 == 0) ? B : V;
  const float* p1 = base1 + h * DD + sub * 4;
  const float* p2 = base2 + h * DD + sub * 4;

  const unsigned lb  = (unsigned)(uintptr_t)(AS3 float*)&smem[0];
  const unsigned vab = lb + (unsigned)(cg * 16);   // vector-read base
  const unsigned vvb = lb + (unsigned)(row * 4);   // v-read base (+1280 imm)

  const int voffb = (h * DD + row) * 4;   // byte offset of (h,row) in one step

  f32x4 s;
  {
    const f32x4* sp = (const f32x4*)(S0 + (size_t)h * DD * DD + row * DD + c0);
    s = *sp;
  }

  auto stage = [&](int tt, int slot) {
    const size_t o = (size_t)tt * HD;
    const float* l = &smem[slot * 512];
    gload_lds16(p1 + o, l);          // R|EW|K|A -> slot[0..1024)
    gload_lds16(p2 + o, l + 256);    // B|V|pad  -> slot[1024..2048)
  };

  auto lds_read = [&](Buf& d, int slot) {
    unsigned va = vab + (unsigned)(slot * 2048);
    unsigned vv = vvb + (unsigned)(slot * 2048);
    asm volatile(
      "ds_read_b128 %0, %6\n\t"
      "ds_read_b128 %1, %6 offset:256\n\t"
      "ds_read_b128 %2, %6 offset:512\n\t"
      "ds_read_b128 %3, %6 offset:768\n\t"
      "ds_read_b128 %4, %6 offset:1024\n\t"
      "ds_read_b32  %5, %7 offset:1280"
      : "=&v"(d.r), "=&v"(d.e), "=&v"(d.k), "=&v"(d.a), "=&v"(d.b), "=&v"(d.vv)
      : "v"(va), "v"(vv) : "memory");
  };

  auto wait_nx1 = [&](Buf& d) {
    asm volatile("s_waitcnt lgkmcnt(6)"
                 : "+v"(d.r), "+v"(d.e), "+v"(d.k), "+v"(d.a), "+v"(d.b),
                   "+v"(d.vv));
  };

  float sa;                 // sa_t = S_{t-1}.a_t, ready at body t entry
  float yprev = 0.0f;       // y_{t-1}, stored at body t
  int   yoff_prev = 2047 * (HD * 4) + voffb;  // body-0 dummy target
                                              // (epilogue overwrites)

  auto body = [&](Buf& cur, Buf& nx1, Buf& nx2, int t) {
    // stage(t+2) (issued at body t-6) resident: bodies t-5..t-1 issued
    // 5 x (1 store + 2 loads) = 15 newer vmem ops -> vmcnt(15).
    asm volatile("s_waitcnt vmcnt(15)" ::: "memory");
    lds_read(nx2, (t + 2) & 7);
    wait_nx1(nx1);

    // ---- state update for step t (sa ready since last body) ----
    const float vv = cur.vv;
    s[0] = fmaf(cur.e[0], s[0], fmaf(sa, cur.b[0], vv * cur.k[0]));
    s[1] = fmaf(cur.e[1], s[1], fmaf(sa, cur.b[1], vv * cur.k[1]));
    s[2] = fmaf(cur.e[2], s[2], fmaf(sa, cur.b[2], vv * cur.k[2]));
    s[3] = fmaf(cur.e[3], s[3], fmaf(sa, cur.b[3], vv * cur.k[3]));

    // ---- both dots (partials) ----
    float qd = dot4(s, nx1.a);   // -> sa_{t+1}
    float yd = dot4(s, cur.r);   // -> y_t

    // ---- store y_{t-1} while reductions run ----
    if (cg == 0) {
      asm volatile("global_store_dword %0, %1, %2"
                   :: "v"(yoff_prev), "v"(yprev), "s"(X) : "memory");
    }
    stage((t + 8) & (T_LEN - 1), t & 7);

    // ---- interleaved dual reduction ----
    duo_reduce(qd, yd);
    sa    = qd;
    yprev = yd;
    yoff_prev = t * (HD * 4) + voffb;
  };

  // Prologue: fill ring (issue order = count order).
  for (int i = 0; i < 8; ++i) {
    stage(i, i);
    __builtin_amdgcn_sched_barrier(0);
  }
  // Slots 0,1 done: stages 2..7 = 12 newer ops.
  asm volatile("s_waitcnt vmcnt(12)" ::: "memory");

  Buf B0, B1, B2, B3;
  lds_read(B0, 0);
  lds_read(B1, 1);
  asm volatile("s_waitcnt lgkmcnt(0)"
               : "+v"(B0.r), "+v"(B0.e), "+v"(B0.k), "+v"(B0.a), "+v"(B0.b),
                 "+v"(B0.vv), "+v"(B1.a));

  // sa_0 = S_init . a_0 (prologue pays one serial reduce)
  sa = row16_reduce(dot4(s, B0.a));

  for (int t = 0; t < T_LEN; t += 4) {
    body(B0, B1, B2, t);
    body(B1, B2, B3, t + 1);
    body(B2, B3, B0, t + 2);
    body(B3, B0, B1, t + 3);
  }

  // Epilogue: final y (t=2047) — overwrites body-0's dummy store.
  if (cg == 0) {
    asm volatile("global_store_dword %0, %1, %2"
                 :: "v"(yoff_prev), "v"(yprev), "s"(X) : "memory");
  }

  *(f32x4*)(SOUT + (size_t)h * DD * DD + row * DD + c0) = s;
}

extern "C" void kernel_launch(void* const* d_in, const int* in_sizes, int n_in,
                              void* d_out, int out_size, void* d_ws, size_t ws_size,
                              hipStream_t stream) {
  // setup_inputs order: seq_length, r, w, k, v, a, b, state2
  const float* r  = (const float*)d_in[1];
  const float* w  = (const float*)d_in[2];
  const float* k  = (const float*)d_in[3];
  const float* v  = (const float*)d_in[4];
  const float* a  = (const float*)d_in[5];
  const float* b  = (const float*)d_in[6];
  const float* s0 = (const float*)d_in[7];

  float* x    = (float*)d_out;                     // (T, H, 1, D)
  float* sout = x + (size_t)T_LEN * HD;            // (H, D, D)

  float* ew = (float*)d_ws;
  (void)ws_size; (void)in_sizes; (void)n_in;

  int n4 = T_LEN * HD / 4;
  hipLaunchKernelGGL(exp_kernel, dim3(1024), dim3(256), 0, stream,
                     (const float4*)w, (float4*)ew, n4);
  hipLaunchKernelGGL(wkv7_scan, dim3(1024), dim3(64), 0, stream,
                     r, ew, k, v, a, b, s0, x, sout);
}